// Round 1
// 966.762 us; speedup vs baseline: 1.6708x; 1.6708x over previous
//
#include <hip/hip_runtime.h>

typedef float f32x4 __attribute__((ext_vector_type(4)));

#define M_DIM 16384L
#define N_DIM 4096L
#define K_DIM 4096L

// ---------------------------------------------------------------------------
// f32 -> OCP e4m3fn, RNE + saturation, bit-exact software version.
// scale is multiplied in first (0.5f for the QDQ activation path, 1.0f for
// the weight path whose values are already exactly e4m3-representable).
// ---------------------------------------------------------------------------
__device__ __forceinline__ unsigned int f32_to_e4m3(float x, float scale) {
  float v = fminf(fmaxf(x * scale, -448.f), 448.f);
  unsigned int u = __float_as_uint(v);
  unsigned int s = (u >> 24) & 0x80u;
  float ax = fabsf(v);
  unsigned int ua = __float_as_uint(ax);
  unsigned int subn = (unsigned int)rintf(ax * 512.0f);   // 0..8, RNE (subnormals)
  unsigned int r = ua + 0x7FFFFu + ((ua >> 20) & 1u);     // RNE to 3 mantissa bits
  unsigned int nrm = ((r >> 20) & 0x7FFu) - 960u;         // rebias 127 -> 7
  unsigned int mag = (ax < 0.015625f) ? subn : nrm;
  return mag | s;
}

__device__ __forceinline__ unsigned int pack4_e4m3(float4 v, float scale) {
  return f32_to_e4m3(v.x, scale) | (f32_to_e4m3(v.y, scale) << 8) |
         (f32_to_e4m3(v.z, scale) << 16) | (f32_to_e4m3(v.w, scale) << 24);
}

// ---------------------------------------------------------------------------
// Kernel 1: f32 -> packed e4m3 quantize (memory-bound).
// ---------------------------------------------------------------------------
__global__ __launch_bounds__(256) void quant_fp8(const float* __restrict__ in,
                                                 unsigned int* __restrict__ out,
                                                 float scale) {
  const long i = (long)blockIdx.x * 256 + threadIdx.x;
  out[i] = pack4_e4m3(reinterpret_cast<const float4*>(in)[i], scale);
}

// ---------------------------------------------------------------------------
// Kernel 2: fp8 GEMM, C[m,n] = 4 * sum_k A[m,k]*B[n,k] + bias[n]
// m145-verified structure: 128x128 tile, BK=64 fp8, 2-barrier K-loop,
// global_load_lds width-16 staging.
//
// LDS layout (this round's change): 16B-granular XOR swizzle on the k-units
// within each 64 B row, keyed on row bits 1-2:
//     LDS (row, unit c) holds global chunk  c ^ ((row>>1)&3).
// Realized as pre-swizzled per-lane GLOBAL source (gld_lds dest stays linear,
// per the wave-uniform-dest rule) + the same XOR on ds_read offsets.
// Applied identically to A and B rows, so sum_k A*B is unchanged bit-exact.
// Effect: fragment ds_read_b64 bank-pairs go from 8 distinct (8-way conflict)
// to all 16 pairs hit 2x per half-wave (the b64 hardware minimum, free).
// ---------------------------------------------------------------------------
__device__ __forceinline__ void gld_lds16(const unsigned char* g, unsigned char* l) {
  __builtin_amdgcn_global_load_lds(
      (const __attribute__((address_space(1))) unsigned int*)g,
      (__attribute__((address_space(3))) unsigned int*)l,
      16, 0, 0);
}

__device__ __forceinline__ uint4 quant16(const float* p, float scale) {
  const float4* q = reinterpret_cast<const float4*>(p);
  uint4 r;
  r.x = pack4_e4m3(q[0], scale);
  r.y = pack4_e4m3(q[1], scale);
  r.z = pack4_e4m3(q[2], scale);
  r.w = pack4_e4m3(q[3], scale);
  return r;
}

template <bool FA, bool FB>
__global__ __launch_bounds__(256) void gemm_fp8(const unsigned char* __restrict__ A8,
                                                const float* __restrict__ Af,
                                                const unsigned char* __restrict__ B8,
                                                const float* __restrict__ Bf,
                                                const float* __restrict__ bias,
                                                float* __restrict__ C) {
  __shared__ unsigned char sA[128 * 64];  // 8 KB, row-major, 64 B per row
  __shared__ unsigned char sB[128 * 64];

  const int t = threadIdx.x;
  const int lane = t & 63;
  const int w = t >> 6;   // wave 0..3
  const int wm = w >> 1;  // 2x2 wave grid, each wave owns 64x64 of C
  const int wn = w & 1;
  const long bx = blockIdx.x;  // N tile
  const long by = blockIdx.y;  // M tile

  f32x4 acc[4][4] = {};

  // staging: 512 chunks of 16 B per tile; thread stages chunks l0 = w*64+lane
  // and l1 = l0+256. chunk l -> row l>>2, 16B-col l&3.
  // Source column is XOR-swizzled by row bits 1-2 (involution).
  const int l0 = w * 64 + lane;
  const int l1 = l0 + 256;
  const int r0 = l0 >> 2, c0 = (l0 & 3) ^ ((l0 >> 3) & 3);
  const int r1 = l1 >> 2, c1 = (l1 & 3) ^ ((l1 >> 3) & 3);

  const unsigned char* gA0 = nullptr; const unsigned char* gA1 = nullptr;
  const float* fA0 = nullptr;         const float* fA1 = nullptr;
  if constexpr (FA) {
    fA0 = Af + (by * 128 + r0) * K_DIM + c0 * 16;
    fA1 = Af + (by * 128 + r1) * K_DIM + c1 * 16;
  } else {
    gA0 = A8 + (by * 128 + r0) * K_DIM + c0 * 16;
    gA1 = A8 + (by * 128 + r1) * K_DIM + c1 * 16;
  }
  const unsigned char* gB0 = nullptr; const unsigned char* gB1 = nullptr;
  const float* fB0 = nullptr;         const float* fB1 = nullptr;
  if constexpr (FB) {
    fB0 = Bf + (bx * 128 + r0) * K_DIM + c0 * 16;
    fB1 = Bf + (bx * 128 + r1) * K_DIM + c1 * 16;
  } else {
    gB0 = B8 + (bx * 128 + r0) * K_DIM + c0 * 16;
    gB1 = B8 + (bx * 128 + r1) * K_DIM + c1 * 16;
  }

  unsigned char* lA0 = sA + w * 1024;         // wave-uniform; HW adds lane*16
  unsigned char* lA1 = sA + 4096 + w * 1024;
  unsigned char* lB0 = sB + w * 1024;
  unsigned char* lB1 = sB + 4096 + w * 1024;

  // fragment offsets: A[m][k] lane map m=lane&15, k=8*(lane>>4)+byte per k-step.
  // Lane wants global 16B-unit u = kq>>1 (and u^2 for the second mfma), intra
  // half (kq&1)*8.  Under the swizzle that unit lives at position u ^ ((row>>1)&3);
  // row = frow + 16i (+64wm/wn), so (row>>1)&3 == (frow>>1)&3 for all i.
  const int frow = lane & 15;
  const int kq = lane >> 4;
  const int swz = (frow >> 1) & 3;
  const int off0 = frow * 64 + ((((kq >> 1) ^ swz) << 4) | ((kq & 1) << 3));
  const int off1 = off0 ^ 32;            // second k-half: unit u^2 -> byte ^32
  const unsigned char* sAw = sA + wm * 4096;  // wm*64 rows
  const unsigned char* sBw = sB + wn * 4096;

  for (int kt = 0; kt < (int)(K_DIM / 64); ++kt) {
    if constexpr (FA) {
      *reinterpret_cast<uint4*>(sA + l0 * 16) = quant16(fA0, 0.5f);
      *reinterpret_cast<uint4*>(sA + l1 * 16) = quant16(fA1, 0.5f);
      fA0 += 64; fA1 += 64;
    } else {
      gld_lds16(gA0, lA0);
      gld_lds16(gA1, lA1);
      gA0 += 64; gA1 += 64;
    }
    if constexpr (FB) {
      *reinterpret_cast<uint4*>(sB + l0 * 16) = quant16(fB0, 1.0f);
      *reinterpret_cast<uint4*>(sB + l1 * 16) = quant16(fB1, 1.0f);
      fB0 += 64; fB1 += 64;
    } else {
      gld_lds16(gB0, lB0);
      gld_lds16(gB1, lB1);
      gB0 += 64; gB1 += 64;
    }
    __syncthreads();  // drains vmcnt (global_load_lds) + lgkmcnt (ds_write)

    long a0[4], a1[4], b0[4], b1[4];
#pragma unroll
    for (int i = 0; i < 4; ++i) {
      a0[i] = *reinterpret_cast<const long*>(sAw + i * 1024 + off0);
      a1[i] = *reinterpret_cast<const long*>(sAw + i * 1024 + off1);
      b0[i] = *reinterpret_cast<const long*>(sBw + i * 1024 + off0);
      b1[i] = *reinterpret_cast<const long*>(sBw + i * 1024 + off1);
    }

#pragma unroll
    for (int i = 0; i < 4; ++i) {
#pragma unroll
      for (int j = 0; j < 4; ++j) {
        acc[i][j] = __builtin_amdgcn_mfma_f32_16x16x32_fp8_fp8(a0[i], b0[j], acc[i][j], 0, 0, 0);
        acc[i][j] = __builtin_amdgcn_mfma_f32_16x16x32_fp8_fp8(a1[i], b1[j], acc[i][j], 0, 0, 0);
      }
    }
    __syncthreads();
  }

  // epilogue: 16x16 C/D map: n = lane&15 (+16j), m = 4*(lane>>4)+reg (+16i)
  const long gm0 = by * 128 + wm * 64 + kq * 4;
  const long gn0 = bx * 128 + wn * 64 + frow;
#pragma unroll
  for (int j = 0; j < 4; ++j) {
    const long gn = gn0 + j * 16;
    const float bv = bias[gn];
#pragma unroll
    for (int i = 0; i < 4; ++i) {
      float* Cp = C + (gm0 + i * 16) * N_DIM + gn;
#pragma unroll
      for (int r = 0; r < 4; ++r) {
        Cp[(long)r * N_DIM] = acc[i][j][r] * 4.0f + bv;
      }
    }
  }
}

// ---------------------------------------------------------------------------
extern "C" void kernel_launch(void* const* d_in, const int* in_sizes, int n_in,
                              void* d_out, int out_size, void* d_ws, size_t ws_size,
                              hipStream_t stream) {
  const float* inp = (const float*)d_in[0];   // [4,4096,4096] f32
  const float* wgt = (const float*)d_in[1];   // [4096,4096] f32 (fp8 values upcast by harness)
  const float* bias = (const float*)d_in[2];  // [4096] f32
  float* out = (float*)d_out;

  dim3 grid((unsigned)(N_DIM / 128), (unsigned)(M_DIM / 128));  // 32 x 128
  const size_t A_BYTES = (size_t)(M_DIM * K_DIM);      // 64 MB
  const size_t B_BYTES = (size_t)(N_DIM * K_DIM);      // 16 MB

  if (ws_size >= A_BYTES + B_BYTES) {
    // main path: pre-quantize both operands into d_ws, pure fp8 GEMM
    unsigned char* aq = (unsigned char*)d_ws;
    unsigned char* wq = (unsigned char*)d_ws + A_BYTES;
    quant_fp8<<<dim3((unsigned)(M_DIM * K_DIM / 1024)), dim3(256), 0, stream>>>(
        inp, (unsigned int*)aq, 0.5f);
    quant_fp8<<<dim3((unsigned)(N_DIM * K_DIM / 1024)), dim3(256), 0, stream>>>(
        wgt, (unsigned int*)wq, 1.0f);
    gemm_fp8<false, false><<<grid, dim3(256), 0, stream>>>(aq, nullptr, wq, nullptr, bias, out);
  } else if (ws_size >= B_BYTES) {
    // quantize weight only; fuse A-quant into staging
    unsigned char* wq = (unsigned char*)d_ws;
    quant_fp8<<<dim3((unsigned)(N_DIM * K_DIM / 1024)), dim3(256), 0, stream>>>(
        wgt, (unsigned int*)wq, 1.0f);
    gemm_fp8<true, false><<<grid, dim3(256), 0, stream>>>(nullptr, inp, wq, nullptr, bias, out);
  } else {
    // no scratch: fuse both quantizations into staging
    gemm_fp8<true, true><<<grid, dim3(256), 0, stream>>>(nullptr, inp, nullptr, wgt, bias, out);
  }
}

// Round 2
// 772.292 us; speedup vs baseline: 2.0916x; 1.2518x over previous
//
#include <hip/hip_runtime.h>

typedef float f32x4 __attribute__((ext_vector_type(4)));
typedef float f32x16 __attribute__((ext_vector_type(16)));
typedef int i32x4 __attribute__((ext_vector_type(4)));
typedef int i32x8 __attribute__((ext_vector_type(8)));

#define M_DIM 16384L
#define N_DIM 4096L
#define K_DIM 4096L

// ---------------------------------------------------------------------------
// f32 -> OCP e4m3fn, RNE + saturation, bit-exact software version.
// scale is multiplied in first (0.5f for the QDQ activation path, 1.0f for
// the weight path whose values are already exactly e4m3-representable).
// ---------------------------------------------------------------------------
__device__ __forceinline__ unsigned int f32_to_e4m3(float x, float scale) {
  float v = fminf(fmaxf(x * scale, -448.f), 448.f);
  unsigned int u = __float_as_uint(v);
  unsigned int s = (u >> 24) & 0x80u;
  float ax = fabsf(v);
  unsigned int ua = __float_as_uint(ax);
  unsigned int subn = (unsigned int)rintf(ax * 512.0f);   // 0..8, RNE (subnormals)
  unsigned int r = ua + 0x7FFFFu + ((ua >> 20) & 1u);     // RNE to 3 mantissa bits
  unsigned int nrm = ((r >> 20) & 0x7FFu) - 960u;         // rebias 127 -> 7
  unsigned int mag = (ax < 0.015625f) ? subn : nrm;
  return mag | s;
}

__device__ __forceinline__ unsigned int pack4_e4m3(float4 v, float scale) {
  return f32_to_e4m3(v.x, scale) | (f32_to_e4m3(v.y, scale) << 8) |
         (f32_to_e4m3(v.z, scale) << 16) | (f32_to_e4m3(v.w, scale) << 24);
}

// ---------------------------------------------------------------------------
// Kernel 1: f32 -> packed e4m3 quantize (memory-bound).
// ---------------------------------------------------------------------------
__global__ __launch_bounds__(256) void quant_fp8(const float* __restrict__ in,
                                                 unsigned int* __restrict__ out,
                                                 float scale) {
  const long i = (long)blockIdx.x * 256 + threadIdx.x;
  out[i] = pack4_e4m3(reinterpret_cast<const float4*>(in)[i], scale);
}

// ---------------------------------------------------------------------------
// Kernel 2: fp8 GEMM, C[m,n] = 4 * sum_k A[m,k]*B[n,k] + bias[n]
// 128x128 tile, BK=64 fp8, 2-barrier K-loop, global_load_lds width-16
// staging, 16B-unit XOR-swizzled LDS (verified R1: conflicts at b64 floor).
//
// This round: MFMA swapped to the block-scaled MX instruction
//   mfma_scale_f32_32x32x64_f8f6f4  (fmtA=fmtB=0 -> e4m3, scales = e8m0 127
//   = 1.0) which computes bit-identical plain fp8 dot products at ~2.1x the
//   non-scaled fp8 rate (m148 precedent).
// Wave owns 64x64 of C = 2x2 fragments of 32x32. Per K-tile per wave:
//   8 x ds_read_b128 (two 16B units per 32B fragment, swizzle positions
//   p and p^1) + 4 MFMA.
// Fragment map (32x32x64): lane holds row lane&31, K-bytes [32*(lane>>5),+32).
// Bank check: uniform 8 lanes/bank = b128 structural floor (conflict-free).
// ---------------------------------------------------------------------------
__device__ __forceinline__ void gld_lds16(const unsigned char* g, unsigned char* l) {
  __builtin_amdgcn_global_load_lds(
      (const __attribute__((address_space(1))) unsigned int*)g,
      (__attribute__((address_space(3))) unsigned int*)l,
      16, 0, 0);
}

__device__ __forceinline__ uint4 quant16(const float* p, float scale) {
  const float4* q = reinterpret_cast<const float4*>(p);
  uint4 r;
  r.x = pack4_e4m3(q[0], scale);
  r.y = pack4_e4m3(q[1], scale);
  r.z = pack4_e4m3(q[2], scale);
  r.w = pack4_e4m3(q[3], scale);
  return r;
}

template <bool FA, bool FB>
__global__ __launch_bounds__(256) void gemm_fp8(const unsigned char* __restrict__ A8,
                                                const float* __restrict__ Af,
                                                const unsigned char* __restrict__ B8,
                                                const float* __restrict__ Bf,
                                                const float* __restrict__ bias,
                                                float* __restrict__ C) {
  __shared__ unsigned char sA[128 * 64];  // 8 KB, row-major, 64 B per row
  __shared__ unsigned char sB[128 * 64];

  const int t = threadIdx.x;
  const int lane = t & 63;
  const int w = t >> 6;   // wave 0..3
  const int wm = w >> 1;  // 2x2 wave grid, each wave owns 64x64 of C
  const int wn = w & 1;
  const long bx = blockIdx.x;  // N tile
  const long by = blockIdx.y;  // M tile

  f32x16 acc[2][2] = {};

  // staging: 512 chunks of 16 B per tile; thread stages chunks l0 = w*64+lane
  // and l1 = l0+256. chunk l -> row l>>2, 16B-col l&3.
  // Source column is XOR-swizzled by row bits 1-2 (involution):
  //   LDS (row, unit p) holds global unit  p ^ ((row>>1)&3).
  const int l0 = w * 64 + lane;
  const int l1 = l0 + 256;
  const int r0 = l0 >> 2, c0 = (l0 & 3) ^ ((l0 >> 3) & 3);
  const int r1 = l1 >> 2, c1 = (l1 & 3) ^ ((l1 >> 3) & 3);

  const unsigned char* gA0 = nullptr; const unsigned char* gA1 = nullptr;
  const float* fA0 = nullptr;         const float* fA1 = nullptr;
  if constexpr (FA) {
    fA0 = Af + (by * 128 + r0) * K_DIM + c0 * 16;
    fA1 = Af + (by * 128 + r1) * K_DIM + c1 * 16;
  } else {
    gA0 = A8 + (by * 128 + r0) * K_DIM + c0 * 16;
    gA1 = A8 + (by * 128 + r1) * K_DIM + c1 * 16;
  }
  const unsigned char* gB0 = nullptr; const unsigned char* gB1 = nullptr;
  const float* fB0 = nullptr;         const float* fB1 = nullptr;
  if constexpr (FB) {
    fB0 = Bf + (bx * 128 + r0) * K_DIM + c0 * 16;
    fB1 = Bf + (bx * 128 + r1) * K_DIM + c1 * 16;
  } else {
    gB0 = B8 + (bx * 128 + r0) * K_DIM + c0 * 16;
    gB1 = B8 + (bx * 128 + r1) * K_DIM + c1 * 16;
  }

  unsigned char* lA0 = sA + w * 1024;         // wave-uniform; HW adds lane*16
  unsigned char* lA1 = sA + 4096 + w * 1024;
  unsigned char* lB0 = sB + w * 1024;
  unsigned char* lB1 = sB + 4096 + w * 1024;

  // fragment addressing for mfma_scale_f32_32x32x64_f8f6f4:
  // lane reads row r32 = lane&31 (+32*frag +64*wm/wn), K-bytes
  // [32*(lane>>5), +32) = 16B units u_lo = 2*(lane>>5), u_lo+1.
  // Swizzled positions: p_lo = u_lo ^ key, p_lo^1 (u_lo even), with
  // key = (row>>1)&3 = (lane>>1)&3 (frag/wave offsets are multiples of 32).
  const int r32 = lane & 31;
  const int key = (lane >> 1) & 3;
  const int p_lo = ((lane >> 5) << 1) ^ key;
  const unsigned char* sAw = sA + wm * 4096;  // wm*64 rows
  const unsigned char* sBw = sB + wn * 4096;

  for (int kt = 0; kt < (int)(K_DIM / 64); ++kt) {
    if constexpr (FA) {
      *reinterpret_cast<uint4*>(sA + l0 * 16) = quant16(fA0, 0.5f);
      *reinterpret_cast<uint4*>(sA + l1 * 16) = quant16(fA1, 0.5f);
      fA0 += 64; fA1 += 64;
    } else {
      gld_lds16(gA0, lA0);
      gld_lds16(gA1, lA1);
      gA0 += 64; gA1 += 64;
    }
    if constexpr (FB) {
      *reinterpret_cast<uint4*>(sB + l0 * 16) = quant16(fB0, 1.0f);
      *reinterpret_cast<uint4*>(sB + l1 * 16) = quant16(fB1, 1.0f);
      fB0 += 64; fB1 += 64;
    } else {
      gld_lds16(gB0, lB0);
      gld_lds16(gB1, lB1);
      gB0 += 64; gB1 += 64;
    }
    __syncthreads();  // drains vmcnt (global_load_lds) + lgkmcnt (ds_write)

    i32x8 af[2], bf[2];
#pragma unroll
    for (int i = 0; i < 2; ++i) {
      const unsigned char* pa = sAw + (i * 32 + r32) * 64;
      i32x4 alo = *reinterpret_cast<const i32x4*>(pa + p_lo * 16);
      i32x4 ahi = *reinterpret_cast<const i32x4*>(pa + (p_lo ^ 1) * 16);
      af[i] = i32x8{alo[0], alo[1], alo[2], alo[3], ahi[0], ahi[1], ahi[2], ahi[3]};
      const unsigned char* pb = sBw + (i * 32 + r32) * 64;
      i32x4 blo = *reinterpret_cast<const i32x4*>(pb + p_lo * 16);
      i32x4 bhi = *reinterpret_cast<const i32x4*>(pb + (p_lo ^ 1) * 16);
      bf[i] = i32x8{blo[0], blo[1], blo[2], blo[3], bhi[0], bhi[1], bhi[2], bhi[3]};
    }

#pragma unroll
    for (int i = 0; i < 2; ++i) {
#pragma unroll
      for (int j = 0; j < 2; ++j) {
        // fmtA=0 (e4m3), fmtB=0, scales = e8m0 127 (=1.0) in all bytes
        acc[i][j] = __builtin_amdgcn_mfma_scale_f32_32x32x64_f8f6f4(
            af[i], bf[j], acc[i][j], 0, 0, 0, 0x7F7F7F7F, 0, 0x7F7F7F7F);
      }
    }
    __syncthreads();
  }

  // epilogue: 32x32 C/D map: col(n) = lane&31, row(m) = (r&3)+8*(r>>2)+4*(lane>>5)
  const int mrow = 4 * (lane >> 5);
  const long gm_base = by * 128 + wm * 64;
  const long gn_base = bx * 128 + wn * 64 + r32;
#pragma unroll
  for (int nj = 0; nj < 2; ++nj) {
    const long gn = gn_base + nj * 32;
    const float bv = bias[gn];
#pragma unroll
    for (int mi = 0; mi < 2; ++mi) {
#pragma unroll
      for (int r = 0; r < 16; ++r) {
        const long gm = gm_base + mi * 32 + (r & 3) + 8 * (r >> 2) + mrow;
        C[gm * N_DIM + gn] = acc[mi][nj][r] * 4.0f + bv;
      }
    }
  }
}

// ---------------------------------------------------------------------------
extern "C" void kernel_launch(void* const* d_in, const int* in_sizes, int n_in,
                              void* d_out, int out_size, void* d_ws, size_t ws_size,
                              hipStream_t stream) {
  const float* inp = (const float*)d_in[0];   // [4,4096,4096] f32
  const float* wgt = (const float*)d_in[1];   // [4096,4096] f32 (fp8 values upcast by harness)
  const float* bias = (const float*)d_in[2];  // [4096] f32
  float* out = (float*)d_out;

  dim3 grid((unsigned)(N_DIM / 128), (unsigned)(M_DIM / 128));  // 32 x 128
  const size_t A_BYTES = (size_t)(M_DIM * K_DIM);      // 64 MB
  const size_t B_BYTES = (size_t)(N_DIM * K_DIM);      // 16 MB

  if (ws_size >= A_BYTES + B_BYTES) {
    // main path: pre-quantize both operands into d_ws, pure fp8 GEMM
    unsigned char* aq = (unsigned char*)d_ws;
    unsigned char* wq = (unsigned char*)d_ws + A_BYTES;
    quant_fp8<<<dim3((unsigned)(M_DIM * K_DIM / 1024)), dim3(256), 0, stream>>>(
        inp, (unsigned int*)aq, 0.5f);
    quant_fp8<<<dim3((unsigned)(N_DIM * K_DIM / 1024)), dim3(256), 0, stream>>>(
        wgt, (unsigned int*)wq, 1.0f);
    gemm_fp8<false, false><<<grid, dim3(256), 0, stream>>>(aq, nullptr, wq, nullptr, bias, out);
  } else if (ws_size >= B_BYTES) {
    // quantize weight only; fuse A-quant into staging
    unsigned char* wq = (unsigned char*)d_ws;
    quant_fp8<<<dim3((unsigned)(N_DIM * K_DIM / 1024)), dim3(256), 0, stream>>>(
        wgt, (unsigned int*)wq, 1.0f);
    gemm_fp8<true, false><<<grid, dim3(256), 0, stream>>>(nullptr, inp, wq, nullptr, bias, out);
  } else {
    // no scratch: fuse both quantizations into staging
    gemm_fp8<true, true><<<grid, dim3(256), 0, stream>>>(nullptr, inp, nullptr, wgt, bias, out);
  }
}